// Round 9
// baseline (4347.610 us; speedup 1.0000x reference)
//
#include <hip/hip_runtime.h>
#include <hip/hip_bf16.h>

#define H 128
#define NSTEPS 8
#define DT_MAXF 0.125f
#define WAVES 4
#define PPW 16            // points per wave (one 16x16 MFMA N-tile now)
#define PPB (WAVES*PPW)   // 64 points per block

typedef __attribute__((ext_vector_type(8))) short short8;   // 8 bf16 MFMA A/B frag
typedef __attribute__((ext_vector_type(4))) float floatx4;  // MFMA C/D frag

__device__ __forceinline__ float fast_tanh(float x) {
    float e = __builtin_amdgcn_exp2f(x * 2.8853900817779268f); // 2*log2(e)
    float r = __builtin_amdgcn_rcpf(e + 1.0f);
    return 1.0f - 2.0f * r;
}
__device__ __forceinline__ unsigned f2bf(float x) {           // fp32 -> bf16 bits, RNE (init-time)
    unsigned u = __float_as_uint(x);
    return (u + 0x7FFFu + ((u >> 16) & 1u)) >> 16;
}
__device__ __forceinline__ unsigned pk2(float a, float b) {   // packed bf16 cvt via union pun
    union { __hip_bfloat162 h; unsigned u; } U;
    U.h = __float22bfloat162_rn(make_float2(a, b));
    return U.u;
}
__device__ __forceinline__ short8 pack_bf8(const float* z) {
    union { unsigned u[4]; short8 s; } U;
    U.u[0] = pk2(z[0], z[1]); U.u[1] = pk2(z[2], z[3]);
    U.u[2] = pk2(z[4], z[5]); U.u[3] = pk2(z[6], z[7]);
    return U.s;
}

// Transposed MFMA orientation: A = W2^T (units as M), B = per-point h-frags
// (points as N). C/D col = lane&15 = THE LANE'S OWN POINT -> reduction is a
// 2-stage xor over the 4 q-replicas, state lives in registers, no sel4, no
// LDS round-trips in the step loop. VALU-visible set fits 128 VGPR at
// 2 waves/SIMD -> spill-free at full occupancy (r7 proved spill-free helps,
// r8 proved 128-cap spills with the old point-major layout).
__global__ __launch_bounds__(256, 2)
void velwarp(const float* __restrict__ code, const float* __restrict__ pos,
             const float* __restrict__ t1g, const float* __restrict__ t2g,
             const float* __restrict__ W1, const float* __restrict__ b1,
             const float* __restrict__ W2, const float* __restrict__ b2,
             const float* __restrict__ W3, const float* __restrict__ b3,
             float* __restrict__ out, int N)
{
    __shared__ __align__(16) unsigned Wbuf[H*H/2];      // 32KB: W1 fp32 (init) then W2 bf16 frag-linear
    __shared__ __align__(16) float baseS[WAVES*8*64*4]; // 32KB: per-lane base1 (self-owned slots)
    __shared__ __align__(16) float W1xc[4][H];          // W1xc[c][u] = W1[64+c][u]
    __shared__ __align__(16) float4 W3s4[H];            // (W3[u][0..2], b2[u])

    const int tid = threadIdx.x;
    const int w   = tid >> 6;
    const int L   = tid & 63;
    const int m   = L & 15;      // this lane's point (C/D col); also z1-prep row
    const int q   = L >> 4;      // k-quad in frags; C/D row group = q*4+reg
    const int pb  = blockIdx.x * PPB + w * PPW;
    const int p   = pb + m;      // global point index (replicated over 4 q-lanes)

    // ---- stage W1 rows [0:64) as fp32 into Wbuf; small tables
    {
        const float4* s4 = (const float4*)W1;
        float4* d4 = (float4*)Wbuf;
        #pragma unroll 4
        for (int i = tid; i < (64*H)/4; i += 256) d4[i] = s4[i];
    }
    for (int idx = tid; idx < 4*H; idx += 256) {
        int c = idx >> 7, u = idx & (H-1);
        W1xc[c][u] = W1[(64 + c)*H + u];
    }
    for (int idx = tid; idx < H; idx += 256)
        W3s4[idx] = make_float4(W3[idx*3+0], W3[idx*3+1], W3[idx*3+2], b2[idx]);
    __syncthreads();

    // ---- base1[s][j] = b1[u] + code[point m] . W1[:64, u],  u = s*32 + q*8 + j
    //      computed in registers (init only), then parked in LDS
    {
        float base1[4][8];
        #pragma unroll
        for (int s = 0; s < 4; ++s) {
            float4 ba = *(const float4*)&b1[s*32 + q*8];
            float4 bb = *(const float4*)&b1[s*32 + q*8 + 4];
            base1[s][0]=ba.x; base1[s][1]=ba.y; base1[s][2]=ba.z; base1[s][3]=ba.w;
            base1[s][4]=bb.x; base1[s][5]=bb.y; base1[s][6]=bb.z; base1[s][7]=bb.w;
        }
        const float* Ws = (const float*)Wbuf;
        const float* crow = code + (size_t)p * 64;
        for (int i = 0; i < 64; ++i) {
            float c = crow[i];
            #pragma unroll
            for (int s = 0; s < 4; ++s) {
                const float* wrp = &Ws[i*H + s*32 + q*8];
                float4 wa = *(const float4*)wrp;
                float4 wb = *(const float4*)(wrp + 4);
                base1[s][0] = fmaf(c, wa.x, base1[s][0]);
                base1[s][1] = fmaf(c, wa.y, base1[s][1]);
                base1[s][2] = fmaf(c, wa.z, base1[s][2]);
                base1[s][3] = fmaf(c, wa.w, base1[s][3]);
                base1[s][4] = fmaf(c, wb.x, base1[s][4]);
                base1[s][5] = fmaf(c, wb.y, base1[s][5]);
                base1[s][6] = fmaf(c, wb.z, base1[s][6]);
                base1[s][7] = fmaf(c, wb.w, base1[s][7]);
            }
        }
        float4* b4 = (float4*)baseS;
        #pragma unroll
        for (int s = 0; s < 4; ++s) {
            b4[(w*8 + s*2 + 0)*64 + L] = make_float4(base1[s][0], base1[s][1], base1[s][2], base1[s][3]);
            b4[(w*8 + s*2 + 1)*64 + L] = make_float4(base1[s][4], base1[s][5], base1[s][6], base1[s][7]);
        }
    }
    __syncthreads();

    // ---- pack W2 -> bf16 fragment-linear: chunk(t,s,lane) = W2[k][u] with
    //      u = t*16+(ln&15), k = s*32+(ln>>4)*8+j  == A-frag layout for A=W2^T
    for (int ch = tid; ch < 2048; ch += 256) {
        int ln = ch & 63, ts = ch >> 6;
        int s = ts & 3, t = ts >> 2;
        int k0 = s*32 + (ln >> 4)*8, n = t*16 + (ln & 15);
        unsigned pk0 = f2bf(W2[(k0+0)*H + n]) | (f2bf(W2[(k0+1)*H + n]) << 16);
        unsigned pk1 = f2bf(W2[(k0+2)*H + n]) | (f2bf(W2[(k0+3)*H + n]) << 16);
        unsigned pk2_ = f2bf(W2[(k0+4)*H + n]) | (f2bf(W2[(k0+5)*H + n]) << 16);
        unsigned pk3 = f2bf(W2[(k0+6)*H + n]) | (f2bf(W2[(k0+7)*H + n]) << 16);
        ((uint4*)Wbuf)[ch] = make_uint4(pk0, pk1, pk2_, pk3);
    }

    // ---- per-lane point state (replicated over the 4 q-lanes of point m)
    float px_ = pos[p*3+0], py_ = pos[p*3+1], pz_ = pos[p*3+2];
    float tc_ = t1g[p];
    float off_ = tc_ - t2g[p];
    float D[9];
    #pragma unroll
    for (int j = 0; j < 9; ++j) D[j] = (j==0||j==4||j==8) ? 1.0f : 0.0f;
    const float b30 = b3[0], b31 = b3[1], b32 = b3[2];
    __syncthreads();

    const short8* Bf = (const short8*)Wbuf;
    const float4* base4 = (const float4*)baseS;

    for (int step = 0; step < NSTEPS; ++step) {
        // ======== eval A: v(x,t) ========
        floatx4 accA[8];
        #pragma unroll
        for (int t = 0; t < 8; ++t) accA[t] = (floatx4){0.f,0.f,0.f,0.f};
        {
            float4 xt = make_float4(px_, py_, pz_, tc_);
            #pragma unroll
            for (int s = 0; s < 4; ++s) {
                const int u0 = s*32 + q*8;
                float h[8];
                #pragma unroll
                for (int jh = 0; jh < 8; jh += 4) {
                    float4 bb = base4[(w*8 + s*2 + (jh >> 2))*64 + L];
                    float4 wx = *(const float4*)&W1xc[0][u0+jh];
                    float4 wy = *(const float4*)&W1xc[1][u0+jh];
                    float4 wz = *(const float4*)&W1xc[2][u0+jh];
                    float4 wt = *(const float4*)&W1xc[3][u0+jh];
                    h[jh+0] = fast_tanh(fmaf(xt.w,wt.x, fmaf(xt.z,wz.x, fmaf(xt.y,wy.x, fmaf(xt.x,wx.x, bb.x)))));
                    h[jh+1] = fast_tanh(fmaf(xt.w,wt.y, fmaf(xt.z,wz.y, fmaf(xt.y,wy.y, fmaf(xt.x,wx.y, bb.y)))));
                    h[jh+2] = fast_tanh(fmaf(xt.w,wt.z, fmaf(xt.z,wz.z, fmaf(xt.y,wy.z, fmaf(xt.x,wx.z, bb.z)))));
                    h[jh+3] = fast_tanh(fmaf(xt.w,wt.w, fmaf(xt.z,wz.w, fmaf(xt.y,wy.w, fmaf(xt.x,wx.w, bb.w)))));
                }
                short8 bf = pack_bf8(h);
                #pragma unroll
                for (int t = 0; t < 8; ++t)
                    accA[t] = __builtin_amdgcn_mfma_f32_16x16x32_bf16(Bf[(t*4+s)*64 + L], bf, accA[t], 0, 0, 0);
            }
        }
        float vAx = 0.f, vAy = 0.f, vAz = 0.f;
        #pragma unroll
        for (int t = 0; t < 8; ++t) {
            #pragma unroll
            for (int reg = 0; reg < 4; ++reg) {
                float4 w3q = W3s4[t*16 + q*4 + reg];  // broadcast over 16 lanes
                float h2 = fast_tanh(accA[t][reg] + w3q.w);
                vAx = fmaf(h2, w3q.x, vAx);
                vAy = fmaf(h2, w3q.y, vAy);
                vAz = fmaf(h2, w3q.z, vAz);
            }
        }
        vAx += __shfl_xor(vAx, 16, 64); vAx += __shfl_xor(vAx, 32, 64);
        vAy += __shfl_xor(vAy, 16, 64); vAy += __shfl_xor(vAy, 32, 64);
        vAz += __shfl_xor(vAz, 16, 64); vAz += __shfl_xor(vAz, 32, 64);

        float dt_ = copysignf(fminf(fabsf(off_), DT_MAXF), off_);
        float hd = 0.5f * dt_;
        float mx = px_ - hd*(vAx + b30);
        float my = py_ - hd*(vAy + b31);
        float mz = pz_ - hd*(vAz + b32);
        float tm = tc_ - hd;

        // ======== eval B: v + Jacobian at midpoint ========
        floatx4 aB0[8], aB1[8], aB2[8], aB3[8];
        #pragma unroll
        for (int t = 0; t < 8; ++t) {
            aB0[t] = (floatx4){0.f,0.f,0.f,0.f};
            aB1[t] = (floatx4){0.f,0.f,0.f,0.f};
            aB2[t] = (floatx4){0.f,0.f,0.f,0.f};
            aB3[t] = (floatx4){0.f,0.f,0.f,0.f};
        }
        {
            float4 xt = make_float4(mx, my, mz, tm);
            #pragma unroll
            for (int s = 0; s < 4; ++s) {
                const int u0 = s*32 + q*8;
                float h[8], d0[8], d1[8], d2[8];
                #pragma unroll
                for (int jh = 0; jh < 8; jh += 4) {
                    float4 bb = base4[(w*8 + s*2 + (jh >> 2))*64 + L];
                    float4 wx = *(const float4*)&W1xc[0][u0+jh];
                    float4 wy = *(const float4*)&W1xc[1][u0+jh];
                    float4 wz = *(const float4*)&W1xc[2][u0+jh];
                    float4 wt = *(const float4*)&W1xc[3][u0+jh];
                    #pragma unroll
                    for (int c4 = 0; c4 < 4; ++c4) {
                        float bbv = (c4==0)?bb.x:(c4==1)?bb.y:(c4==2)?bb.z:bb.w;
                        float wxv = (c4==0)?wx.x:(c4==1)?wx.y:(c4==2)?wx.z:wx.w;
                        float wyv = (c4==0)?wy.x:(c4==1)?wy.y:(c4==2)?wy.z:wy.w;
                        float wzv = (c4==0)?wz.x:(c4==1)?wz.y:(c4==2)?wz.z:wz.w;
                        float wtv = (c4==0)?wt.x:(c4==1)?wt.y:(c4==2)?wt.z:wt.w;
                        int j = jh + c4;
                        float zz = fmaf(xt.w,wtv, fmaf(xt.z,wzv, fmaf(xt.y,wyv, fmaf(xt.x,wxv, bbv))));
                        float hh = fast_tanh(zz);
                        float sd = fmaf(-hh, hh, 1.0f);
                        h[j]  = hh;
                        d0[j] = sd * wxv;
                        d1[j] = sd * wyv;
                        d2[j] = sd * wzv;
                    }
                }
                short8 f0 = pack_bf8(h);
                short8 f1 = pack_bf8(d0);
                short8 f2 = pack_bf8(d1);
                short8 f3 = pack_bf8(d2);
                #pragma unroll
                for (int t = 0; t < 8; ++t) {
                    short8 a = Bf[(t*4+s)*64 + L];
                    aB0[t] = __builtin_amdgcn_mfma_f32_16x16x32_bf16(a, f0, aB0[t], 0, 0, 0);
                    aB1[t] = __builtin_amdgcn_mfma_f32_16x16x32_bf16(a, f1, aB1[t], 0, 0, 0);
                    aB2[t] = __builtin_amdgcn_mfma_f32_16x16x32_bf16(a, f2, aB2[t], 0, 0, 0);
                    aB3[t] = __builtin_amdgcn_mfma_f32_16x16x32_bf16(a, f3, aB3[t], 0, 0, 0);
                }
            }
        }
        float vx = 0.f, vy = 0.f, vz = 0.f;
        float Jr[9];
        #pragma unroll
        for (int oi = 0; oi < 9; ++oi) Jr[oi] = 0.f;
        #pragma unroll
        for (int t = 0; t < 8; ++t) {
            #pragma unroll
            for (int reg = 0; reg < 4; ++reg) {
                float4 w3q = W3s4[t*16 + q*4 + reg];
                float h2 = fast_tanh(aB0[t][reg] + w3q.w);
                float s2 = fmaf(-h2, h2, 1.0f);
                vx = fmaf(h2, w3q.x, vx);
                vy = fmaf(h2, w3q.y, vy);
                vz = fmaf(h2, w3q.z, vz);
                float dd0 = s2*aB1[t][reg], dd1 = s2*aB2[t][reg], dd2 = s2*aB3[t][reg];
                Jr[0] = fmaf(dd0, w3q.x, Jr[0]);
                Jr[1] = fmaf(dd1, w3q.x, Jr[1]);
                Jr[2] = fmaf(dd2, w3q.x, Jr[2]);
                Jr[3] = fmaf(dd0, w3q.y, Jr[3]);
                Jr[4] = fmaf(dd1, w3q.y, Jr[4]);
                Jr[5] = fmaf(dd2, w3q.y, Jr[5]);
                Jr[6] = fmaf(dd0, w3q.z, Jr[6]);
                Jr[7] = fmaf(dd1, w3q.z, Jr[7]);
                Jr[8] = fmaf(dd2, w3q.z, Jr[8]);
            }
        }
        vx += __shfl_xor(vx, 16, 64); vx += __shfl_xor(vx, 32, 64);
        vy += __shfl_xor(vy, 16, 64); vy += __shfl_xor(vy, 32, 64);
        vz += __shfl_xor(vz, 16, 64); vz += __shfl_xor(vz, 32, 64);
        #pragma unroll
        for (int oi = 0; oi < 9; ++oi) {
            Jr[oi] += __shfl_xor(Jr[oi], 16, 64);
            Jr[oi] += __shfl_xor(Jr[oi], 32, 64);
        }
        vx += b30; vy += b31; vz += b32;

        // def + state update, replicated identically in all 4 q-lanes
        float nd[9];
        #pragma unroll
        for (int o = 0; o < 3; ++o)
            #pragma unroll
            for (int c = 0; c < 3; ++c)
                nd[o*3+c] = D[o*3+c] - dt_*(Jr[o*3+0]*D[0*3+c] + Jr[o*3+1]*D[1*3+c] + Jr[o*3+2]*D[2*3+c]);
        #pragma unroll
        for (int j = 0; j < 9; ++j) D[j] = nd[j];
        px_ = fmaf(-dt_, vx, px_);
        py_ = fmaf(-dt_, vy, py_);
        pz_ = fmaf(-dt_, vz, pz_);
        tc_  -= dt_;
        off_ -= dt_;
    }

    // ---- output: q==0 lane of each point writes xyz + deform
    if (q == 0) {
        out[p*3+0] = px_; out[p*3+1] = py_; out[p*3+2] = pz_;
        float* o9 = out + (size_t)N*3 + (size_t)p*9;
        #pragma unroll
        for (int j = 0; j < 9; ++j) o9[j] = D[j];
    }
}

extern "C" void kernel_launch(void* const* d_in, const int* in_sizes, int n_in,
                              void* d_out, int out_size, void* d_ws, size_t ws_size,
                              hipStream_t stream) {
    const float* code = (const float*)d_in[0];
    const float* pos  = (const float*)d_in[1];
    const float* t1   = (const float*)d_in[2];
    const float* t2   = (const float*)d_in[3];
    const float* W1   = (const float*)d_in[4];
    const float* b1   = (const float*)d_in[5];
    const float* W2   = (const float*)d_in[6];
    const float* b2   = (const float*)d_in[7];
    const float* W3   = (const float*)d_in[8];
    const float* b3   = (const float*)d_in[9];
    float* out = (float*)d_out;
    const int N = in_sizes[1] / 3;           // 131072
    const int blocks = N / PPB;              // 2048
    velwarp<<<blocks, 256, 0, stream>>>(code, pos, t1, t2, W1, b1, W2, b2, W3, b3, out, N);
}

// Round 10
// 562.264 us; speedup vs baseline: 7.7323x; 7.7323x over previous
//
#include <hip/hip_runtime.h>
#include <hip/hip_bf16.h>

#define H 128
#define NSTEPS 8
#define DT_MAXF 0.125f
#define WAVES 4
#define PPW 16            // points per wave (one 16x16 MFMA N-tile)
#define PPB (WAVES*PPW)   // 64 points per block

typedef __attribute__((ext_vector_type(8))) short short8;   // 8 bf16 MFMA A/B frag
typedef __attribute__((ext_vector_type(4))) float floatx4;  // MFMA C/D frag

__device__ __forceinline__ float fast_tanh(float x) {
    float e = __builtin_amdgcn_exp2f(x * 2.8853900817779268f); // 2*log2(e)
    float r = __builtin_amdgcn_rcpf(e + 1.0f);
    return 1.0f - 2.0f * r;
}
__device__ __forceinline__ unsigned f2bf(float x) {           // fp32 -> bf16 bits, RNE (init-time)
    unsigned u = __float_as_uint(x);
    return (u + 0x7FFFu + ((u >> 16) & 1u)) >> 16;
}
__device__ __forceinline__ unsigned pk2(float a, float b) {   // packed bf16 cvt via union pun
    union { __hip_bfloat162 h; unsigned u; } U;
    U.h = __float22bfloat162_rn(make_float2(a, b));
    return U.u;
}
__device__ __forceinline__ short8 pack_bf8(const float* z) {
    union { unsigned u[4]; short8 s; } U;
    U.u[0] = pk2(z[0], z[1]); U.u[1] = pk2(z[2], z[3]);
    U.u[2] = pk2(z[4], z[5]); U.u[3] = pk2(z[6], z[7]);
    return U.s;
}

// Transposed MFMA orientation (A = W2^T, B = per-point frags; C/D col = own
// point). r9 proved the math; r9's 8 GB scratch FETCH came from unconstrained
// scheduling across the fully-unrolled MFMA nest (no phase fences -> Bf loads
// hoisted, live ranges exploded). Containment here:
//   (1) sched_barrier(0) after every s-slice
//   (2) eval-B in 2 t-groups of 4 -> 64 live acc floats, frags rebuilt per group
__global__ __launch_bounds__(256, 2)
void velwarp(const float* __restrict__ code, const float* __restrict__ pos,
             const float* __restrict__ t1g, const float* __restrict__ t2g,
             const float* __restrict__ W1, const float* __restrict__ b1,
             const float* __restrict__ W2, const float* __restrict__ b2,
             const float* __restrict__ W3, const float* __restrict__ b3,
             float* __restrict__ out, int N)
{
    __shared__ __align__(16) unsigned Wbuf[H*H/2];      // 32KB: W1 fp32 (init) then W2 bf16 frag-linear
    __shared__ __align__(16) float baseS[WAVES*8*64*4]; // 32KB: per-lane base1 (self-owned slots)
    __shared__ __align__(16) float W1xc[4][H];          // W1xc[c][u] = W1[64+c][u]
    __shared__ __align__(16) float4 W3s4[H];            // (W3[u][0..2], b2[u])

    const int tid = threadIdx.x;
    const int w   = tid >> 6;
    const int L   = tid & 63;
    const int m   = L & 15;      // this lane's point (C/D col); also z1-prep row
    const int q   = L >> 4;      // k-quad in frags; C/D row group = q*4+reg
    const int pb  = blockIdx.x * PPB + w * PPW;
    const int p   = pb + m;      // global point index (replicated over 4 q-lanes)

    // ---- stage W1 rows [0:64) as fp32 into Wbuf; small tables
    {
        const float4* s4 = (const float4*)W1;
        float4* d4 = (float4*)Wbuf;
        #pragma unroll 4
        for (int i = tid; i < (64*H)/4; i += 256) d4[i] = s4[i];
    }
    for (int idx = tid; idx < 4*H; idx += 256) {
        int c = idx >> 7, u = idx & (H-1);
        W1xc[c][u] = W1[(64 + c)*H + u];
    }
    for (int idx = tid; idx < H; idx += 256)
        W3s4[idx] = make_float4(W3[idx*3+0], W3[idx*3+1], W3[idx*3+2], b2[idx]);
    __syncthreads();

    // ---- base1[s][j] = b1[u] + code[point m] . W1[:64, u],  u = s*32 + q*8 + j
    {
        float base1[4][8];
        #pragma unroll
        for (int s = 0; s < 4; ++s) {
            float4 ba = *(const float4*)&b1[s*32 + q*8];
            float4 bb = *(const float4*)&b1[s*32 + q*8 + 4];
            base1[s][0]=ba.x; base1[s][1]=ba.y; base1[s][2]=ba.z; base1[s][3]=ba.w;
            base1[s][4]=bb.x; base1[s][5]=bb.y; base1[s][6]=bb.z; base1[s][7]=bb.w;
        }
        const float* Ws = (const float*)Wbuf;
        const float* crow = code + (size_t)p * 64;
        for (int i = 0; i < 64; ++i) {
            float c = crow[i];
            #pragma unroll
            for (int s = 0; s < 4; ++s) {
                const float* wrp = &Ws[i*H + s*32 + q*8];
                float4 wa = *(const float4*)wrp;
                float4 wb = *(const float4*)(wrp + 4);
                base1[s][0] = fmaf(c, wa.x, base1[s][0]);
                base1[s][1] = fmaf(c, wa.y, base1[s][1]);
                base1[s][2] = fmaf(c, wa.z, base1[s][2]);
                base1[s][3] = fmaf(c, wa.w, base1[s][3]);
                base1[s][4] = fmaf(c, wb.x, base1[s][4]);
                base1[s][5] = fmaf(c, wb.y, base1[s][5]);
                base1[s][6] = fmaf(c, wb.z, base1[s][6]);
                base1[s][7] = fmaf(c, wb.w, base1[s][7]);
            }
        }
        float4* b4 = (float4*)baseS;
        #pragma unroll
        for (int s = 0; s < 4; ++s) {
            b4[(w*8 + s*2 + 0)*64 + L] = make_float4(base1[s][0], base1[s][1], base1[s][2], base1[s][3]);
            b4[(w*8 + s*2 + 1)*64 + L] = make_float4(base1[s][4], base1[s][5], base1[s][6], base1[s][7]);
        }
    }
    __syncthreads();

    // ---- pack W2 -> bf16 fragment-linear == A-frag layout for A = W2^T
    for (int ch = tid; ch < 2048; ch += 256) {
        int ln = ch & 63, ts = ch >> 6;
        int s = ts & 3, t = ts >> 2;
        int k0 = s*32 + (ln >> 4)*8, n = t*16 + (ln & 15);
        unsigned pk0 = f2bf(W2[(k0+0)*H + n]) | (f2bf(W2[(k0+1)*H + n]) << 16);
        unsigned pk1 = f2bf(W2[(k0+2)*H + n]) | (f2bf(W2[(k0+3)*H + n]) << 16);
        unsigned pk2_ = f2bf(W2[(k0+4)*H + n]) | (f2bf(W2[(k0+5)*H + n]) << 16);
        unsigned pk3 = f2bf(W2[(k0+6)*H + n]) | (f2bf(W2[(k0+7)*H + n]) << 16);
        ((uint4*)Wbuf)[ch] = make_uint4(pk0, pk1, pk2_, pk3);
    }

    // ---- per-lane point state (replicated over the 4 q-lanes of point m)
    float px_ = pos[p*3+0], py_ = pos[p*3+1], pz_ = pos[p*3+2];
    float tc_ = t1g[p];
    float off_ = tc_ - t2g[p];
    float D[9];
    #pragma unroll
    for (int j = 0; j < 9; ++j) D[j] = (j==0||j==4||j==8) ? 1.0f : 0.0f;
    const float b30 = b3[0], b31 = b3[1], b32 = b3[2];
    __syncthreads();

    const short8* Bf = (const short8*)Wbuf;
    const float4* base4 = (const float4*)baseS;

    for (int step = 0; step < NSTEPS; ++step) {
        // ======== eval A: v(x,t) ========
        float vAx = 0.f, vAy = 0.f, vAz = 0.f;
        {
            float4 xt = make_float4(px_, py_, pz_, tc_);
            #pragma unroll
            for (int tg = 0; tg < 2; ++tg) {
                floatx4 accA[4];
                #pragma unroll
                for (int tt = 0; tt < 4; ++tt) accA[tt] = (floatx4){0.f,0.f,0.f,0.f};
                #pragma unroll
                for (int s = 0; s < 4; ++s) {
                    const int u0 = s*32 + q*8;
                    float h[8];
                    #pragma unroll
                    for (int jh = 0; jh < 8; jh += 4) {
                        float4 bb = base4[(w*8 + s*2 + (jh >> 2))*64 + L];
                        float4 wx = *(const float4*)&W1xc[0][u0+jh];
                        float4 wy = *(const float4*)&W1xc[1][u0+jh];
                        float4 wz = *(const float4*)&W1xc[2][u0+jh];
                        float4 wt = *(const float4*)&W1xc[3][u0+jh];
                        h[jh+0] = fast_tanh(fmaf(xt.w,wt.x, fmaf(xt.z,wz.x, fmaf(xt.y,wy.x, fmaf(xt.x,wx.x, bb.x)))));
                        h[jh+1] = fast_tanh(fmaf(xt.w,wt.y, fmaf(xt.z,wz.y, fmaf(xt.y,wy.y, fmaf(xt.x,wx.y, bb.y)))));
                        h[jh+2] = fast_tanh(fmaf(xt.w,wt.z, fmaf(xt.z,wz.z, fmaf(xt.y,wy.z, fmaf(xt.x,wx.z, bb.z)))));
                        h[jh+3] = fast_tanh(fmaf(xt.w,wt.w, fmaf(xt.z,wz.w, fmaf(xt.y,wy.w, fmaf(xt.x,wx.w, bb.w)))));
                    }
                    short8 bf = pack_bf8(h);
                    #pragma unroll
                    for (int tt = 0; tt < 4; ++tt)
                        accA[tt] = __builtin_amdgcn_mfma_f32_16x16x32_bf16(Bf[((tg*4+tt)*4+s)*64 + L], bf, accA[tt], 0, 0, 0);
                    __builtin_amdgcn_sched_barrier(0);
                }
                #pragma unroll
                for (int tt = 0; tt < 4; ++tt) {
                    const int t = tg*4 + tt;
                    #pragma unroll
                    for (int reg = 0; reg < 4; ++reg) {
                        float4 w3q = W3s4[t*16 + q*4 + reg];  // broadcast over 16 lanes
                        float h2 = fast_tanh(accA[tt][reg] + w3q.w);
                        vAx = fmaf(h2, w3q.x, vAx);
                        vAy = fmaf(h2, w3q.y, vAy);
                        vAz = fmaf(h2, w3q.z, vAz);
                    }
                }
                __builtin_amdgcn_sched_barrier(0);
            }
        }
        vAx += __shfl_xor(vAx, 16, 64); vAx += __shfl_xor(vAx, 32, 64);
        vAy += __shfl_xor(vAy, 16, 64); vAy += __shfl_xor(vAy, 32, 64);
        vAz += __shfl_xor(vAz, 16, 64); vAz += __shfl_xor(vAz, 32, 64);

        float dt_ = copysignf(fminf(fabsf(off_), DT_MAXF), off_);
        float hd = 0.5f * dt_;
        float mx = px_ - hd*(vAx + b30);
        float my = py_ - hd*(vAy + b31);
        float mz = pz_ - hd*(vAz + b32);
        float tm = tc_ - hd;

        // ======== eval B: v + Jacobian at midpoint, 2 t-groups of 4 ========
        float vx = 0.f, vy = 0.f, vz = 0.f;
        float Jr[9];
        #pragma unroll
        for (int oi = 0; oi < 9; ++oi) Jr[oi] = 0.f;
        {
            float4 xt = make_float4(mx, my, mz, tm);
            #pragma unroll
            for (int tg = 0; tg < 2; ++tg) {
                floatx4 aB0[4], aB1[4], aB2[4], aB3[4];
                #pragma unroll
                for (int tt = 0; tt < 4; ++tt) {
                    aB0[tt] = (floatx4){0.f,0.f,0.f,0.f};
                    aB1[tt] = (floatx4){0.f,0.f,0.f,0.f};
                    aB2[tt] = (floatx4){0.f,0.f,0.f,0.f};
                    aB3[tt] = (floatx4){0.f,0.f,0.f,0.f};
                }
                #pragma unroll
                for (int s = 0; s < 4; ++s) {
                    const int u0 = s*32 + q*8;
                    float h[8], d0[8], d1[8], d2[8];
                    #pragma unroll
                    for (int jh = 0; jh < 8; jh += 4) {
                        float4 bb = base4[(w*8 + s*2 + (jh >> 2))*64 + L];
                        float4 wx = *(const float4*)&W1xc[0][u0+jh];
                        float4 wy = *(const float4*)&W1xc[1][u0+jh];
                        float4 wz = *(const float4*)&W1xc[2][u0+jh];
                        float4 wt = *(const float4*)&W1xc[3][u0+jh];
                        #pragma unroll
                        for (int c4 = 0; c4 < 4; ++c4) {
                            float bbv = (c4==0)?bb.x:(c4==1)?bb.y:(c4==2)?bb.z:bb.w;
                            float wxv = (c4==0)?wx.x:(c4==1)?wx.y:(c4==2)?wx.z:wx.w;
                            float wyv = (c4==0)?wy.x:(c4==1)?wy.y:(c4==2)?wy.z:wy.w;
                            float wzv = (c4==0)?wz.x:(c4==1)?wz.y:(c4==2)?wz.z:wz.w;
                            float wtv = (c4==0)?wt.x:(c4==1)?wt.y:(c4==2)?wt.z:wt.w;
                            int j = jh + c4;
                            float zz = fmaf(xt.w,wtv, fmaf(xt.z,wzv, fmaf(xt.y,wyv, fmaf(xt.x,wxv, bbv))));
                            float hh = fast_tanh(zz);
                            float sd = fmaf(-hh, hh, 1.0f);
                            h[j]  = hh;
                            d0[j] = sd * wxv;
                            d1[j] = sd * wyv;
                            d2[j] = sd * wzv;
                        }
                    }
                    short8 f0 = pack_bf8(h);
                    short8 f1 = pack_bf8(d0);
                    short8 f2 = pack_bf8(d1);
                    short8 f3 = pack_bf8(d2);
                    #pragma unroll
                    for (int tt = 0; tt < 4; ++tt) {
                        short8 a = Bf[((tg*4+tt)*4+s)*64 + L];
                        aB0[tt] = __builtin_amdgcn_mfma_f32_16x16x32_bf16(a, f0, aB0[tt], 0, 0, 0);
                        aB1[tt] = __builtin_amdgcn_mfma_f32_16x16x32_bf16(a, f1, aB1[tt], 0, 0, 0);
                        aB2[tt] = __builtin_amdgcn_mfma_f32_16x16x32_bf16(a, f2, aB2[tt], 0, 0, 0);
                        aB3[tt] = __builtin_amdgcn_mfma_f32_16x16x32_bf16(a, f3, aB3[tt], 0, 0, 0);
                    }
                    __builtin_amdgcn_sched_barrier(0);
                }
                #pragma unroll
                for (int tt = 0; tt < 4; ++tt) {
                    const int t = tg*4 + tt;
                    #pragma unroll
                    for (int reg = 0; reg < 4; ++reg) {
                        float4 w3q = W3s4[t*16 + q*4 + reg];
                        float h2 = fast_tanh(aB0[tt][reg] + w3q.w);
                        float s2 = fmaf(-h2, h2, 1.0f);
                        vx = fmaf(h2, w3q.x, vx);
                        vy = fmaf(h2, w3q.y, vy);
                        vz = fmaf(h2, w3q.z, vz);
                        float dd0 = s2*aB1[tt][reg], dd1 = s2*aB2[tt][reg], dd2 = s2*aB3[tt][reg];
                        Jr[0] = fmaf(dd0, w3q.x, Jr[0]);
                        Jr[1] = fmaf(dd1, w3q.x, Jr[1]);
                        Jr[2] = fmaf(dd2, w3q.x, Jr[2]);
                        Jr[3] = fmaf(dd0, w3q.y, Jr[3]);
                        Jr[4] = fmaf(dd1, w3q.y, Jr[4]);
                        Jr[5] = fmaf(dd2, w3q.y, Jr[5]);
                        Jr[6] = fmaf(dd0, w3q.z, Jr[6]);
                        Jr[7] = fmaf(dd1, w3q.z, Jr[7]);
                        Jr[8] = fmaf(dd2, w3q.z, Jr[8]);
                    }
                }
                __builtin_amdgcn_sched_barrier(0);
            }
        }
        vx += __shfl_xor(vx, 16, 64); vx += __shfl_xor(vx, 32, 64);
        vy += __shfl_xor(vy, 16, 64); vy += __shfl_xor(vy, 32, 64);
        vz += __shfl_xor(vz, 16, 64); vz += __shfl_xor(vz, 32, 64);
        #pragma unroll
        for (int oi = 0; oi < 9; ++oi) {
            Jr[oi] += __shfl_xor(Jr[oi], 16, 64);
            Jr[oi] += __shfl_xor(Jr[oi], 32, 64);
        }
        vx += b30; vy += b31; vz += b32;

        // def + state update, replicated identically in all 4 q-lanes
        float nd[9];
        #pragma unroll
        for (int o = 0; o < 3; ++o)
            #pragma unroll
            for (int c = 0; c < 3; ++c)
                nd[o*3+c] = D[o*3+c] - dt_*(Jr[o*3+0]*D[0*3+c] + Jr[o*3+1]*D[1*3+c] + Jr[o*3+2]*D[2*3+c]);
        #pragma unroll
        for (int j = 0; j < 9; ++j) D[j] = nd[j];
        px_ = fmaf(-dt_, vx, px_);
        py_ = fmaf(-dt_, vy, py_);
        pz_ = fmaf(-dt_, vz, pz_);
        tc_  -= dt_;
        off_ -= dt_;
    }

    // ---- output: q==0 lane of each point writes xyz + deform
    if (q == 0) {
        out[p*3+0] = px_; out[p*3+1] = py_; out[p*3+2] = pz_;
        float* o9 = out + (size_t)N*3 + (size_t)p*9;
        #pragma unroll
        for (int j = 0; j < 9; ++j) o9[j] = D[j];
    }
}

extern "C" void kernel_launch(void* const* d_in, const int* in_sizes, int n_in,
                              void* d_out, int out_size, void* d_ws, size_t ws_size,
                              hipStream_t stream) {
    const float* code = (const float*)d_in[0];
    const float* pos  = (const float*)d_in[1];
    const float* t1   = (const float*)d_in[2];
    const float* t2   = (const float*)d_in[3];
    const float* W1   = (const float*)d_in[4];
    const float* b1   = (const float*)d_in[5];
    const float* W2   = (const float*)d_in[6];
    const float* b2   = (const float*)d_in[7];
    const float* W3   = (const float*)d_in[8];
    const float* b3   = (const float*)d_in[9];
    float* out = (float*)d_out;
    const int N = in_sizes[1] / 3;           // 131072
    const int blocks = N / PPB;              // 2048
    velwarp<<<blocks, 256, 0, stream>>>(code, pos, t1, t2, W1, b1, W2, b2, W3, b3, out, N);
}